// Round 13
// baseline (161.281 us; speedup 1.0000x reference)
//
#include <hip/hip_runtime.h>
#include <hip/hip_bf16.h>

#define NS 32768          // B*S samples
#define EMB 512
#define KDIM 2048
#define BM 128
#define BN 128
#define NITER (KDIM / 32)   // 64

typedef float f32x16 __attribute__((ext_vector_type(16)));
typedef __bf16 bf16x8 __attribute__((ext_vector_type(8)));
typedef __bf16 bf16x2 __attribute__((ext_vector_type(2)));
typedef unsigned int u32;
typedef const __attribute__((address_space(1))) u32* gptr_t;
typedef __attribute__((address_space(3))) u32* lptr_t;

__device__ __forceinline__ void gload_lds16(const void* g, void* l) {
    __builtin_amdgcn_global_load_lds((gptr_t)g, (lptr_t)l, 16, 0, 0);
}

// pack two relu'd floats into one u32 of 2 bf16 (v_cvt_pk_bf16_f32)
__device__ __forceinline__ u32 pkrelu(float lo, float hi) {
    union { bf16x2 h; u32 u; } c;
    c.h[0] = (__bf16)fmaxf(lo, 0.f);
    c.h[1] = (__bf16)fmaxf(hi, 0.f);
    return c.u;
}

__device__ __forceinline__ bf16x8 mk_af(u32 a, u32 b, u32 c, u32 d) {
    union { u32 u[4]; bf16x8 v; } t;
    t.u[0] = a; t.u[1] = b; t.u[2] = c; t.u[3] = d;
    return t.v;
}

// With the hidden-index pre-permutation (verified r5-r12), GEMM1 D regs are
// already in GEMM2 A-frag order: af0 = regs 0..7 packed, af1 = regs 8..15.
__device__ __forceinline__ void h_to_af(const f32x16 h, bf16x8& af0, bf16x8& af1) {
    af0 = mk_af(pkrelu(h[0], h[1]),  pkrelu(h[2], h[3]),
                pkrelu(h[4], h[5]),  pkrelu(h[6], h[7]));
    af1 = mk_af(pkrelu(h[8], h[9]),  pkrelu(h[10], h[11]),
                pkrelu(h[12], h[13]), pkrelu(h[14], h[15]));
}

// ---- prep: W2 -> bf16 (1024 blocks); W1 -> bf16 (16 blocks) ----
__global__ __launch_bounds__(256) void k_prep(const float* __restrict__ W2,
                                              const float* __restrict__ W1,
                                              __hip_bfloat16* __restrict__ W2b,
                                              __hip_bfloat16* __restrict__ W1bg) {
    int t = threadIdx.x;
    if (blockIdx.x < 1024) {
        int i = (blockIdx.x * 256 + t) * 4;
        float4 v = *(const float4*)(W2 + i);
        __hip_bfloat16 o[4];
        o[0] = __float2bfloat16(v.x); o[1] = __float2bfloat16(v.y);
        o[2] = __float2bfloat16(v.z); o[3] = __float2bfloat16(v.w);
        *(ulong1*)(W2b + i) = *(ulong1*)o;
    } else {
        int j = (blockIdx.x - 1024) * 1024 + t * 4;   // 16 blocks x 1024
        float4 w = *(const float4*)(W1 + j);
        __hip_bfloat16 p[4];
        p[0] = __float2bfloat16(w.x); p[1] = __float2bfloat16(w.y);
        p[2] = __float2bfloat16(w.z); p[3] = __float2bfloat16(w.w);
        *(ulong1*)(W1bg + j) = *(ulong1*)p;
    }
}

// ---- fused: C[128,128-tile] = relu(ev @ W1^T + b1) @ W2b^T + b2 ----
// OCCUPANCY round: 3 independent blocks/CU (separate barriers -> phase
// drift -> cross-block overlap of the serial GEMM1/pack chain; r5 proved
// same-block waves in lockstep don't overlap).
//  * BM=128: one 32-row group per wave -> acc = 4 x f32x16 = 64 AGPR.
//  * W1s LDS eliminated: per-lane W1 row (pre-permuted index) loaded 16B
//    from global (L2-resident 32KB), prefetched one iter ahead.
//  * evs LDS eliminated: each lane computes ev for its OWN row in regs.
//  * Bs 3 buffers, prefetch distance 1, one raw s_barrier/iter, vmcnt(3)
//    (3 newer loads in flight: 2 stage + 1 w1f). Skew<=1-barrier safe:
//    writer (T+1)%3 vs laggard reader (T-1)%3 distinct.
//  * LDS = 3x8KB + 4KB b1h = 28KB; launch_bounds(256,3).
__global__ __launch_bounds__(256, 3) void k_gemm(
        const float* __restrict__ x,       // [NS, 8]
        const float* __restrict__ params,  // [8, 3]
        const __hip_bfloat16* __restrict__ W1bg,  // [2048, 8] bf16
        const float* __restrict__ b1,      // [2048]
        const __hip_bfloat16* __restrict__ W2b,   // [512, 2048] bf16
        const float* __restrict__ b2,      // [512]
        float* __restrict__ C) {           // [NS, 512]
    __shared__ __hip_bfloat16 Bs[3][8 * 512];  // 3 x 8 KB
    __shared__ __hip_bfloat16 b1h[KDIM];       // 4 KB (permuted by p) -> 28 KB

    int tid = threadIdx.x, wave = tid >> 6, lane = tid & 63;
    int l31 = lane & 31, half = lane >> 5;
    int bx = blockIdx.x, bm = bx >> 2, bn = bx & 3;

    // per-lane permuted W1 row offset within a 32-chunk (quad swap 1<->2)
    int qq = (l31 >> 2) & 3;
    int prow = l31 + ((qq == 1) ? 4 : (qq == 2) ? -4 : 0);

    // --- ev in REGISTERS for this lane's own output row (dup across halves)
    bf16x8 evB0;
    {
        float K1[8], K2[8];
        #pragma unroll
        for (int i = 0; i < 8; i++) {
            float a = params[i*3+0], b = params[i*3+1], g = params[i*3+2];
            float sa, ca, sb, cb, sg, cg;
            __sincosf(a, &sa, &ca);
            __sincosf(b, &sb, &cb);
            __sincosf(g, &sg, &cg);
            K1[i] = sa*sb*sg + ca*cg;
            K2[i] = cb*sg;
        }
        int n = bm * BM + wave * 32 + l31;
        float4 x0 = *(const float4*)(x + (size_t)n*8);
        float4 x1 = *(const float4*)(x + (size_t)n*8 + 4);
        float xs[8] = {x0.x, x0.y, x0.z, x0.w, x1.x, x1.y, x1.z, x1.w};
        float z[8];
        #pragma unroll
        for (int i = 0; i < 8; i++) {
            float s, c;
            __sincosf(xs[i], &s, &c);
            z[i] = c * K1[i] - s * K2[i];
        }
        float evv[8];
        float p = z[0];
        #pragma unroll
        for (int j = 1; j < 8; j++) { p *= z[j]; evv[j] = p; }
        float sfx = z[7];
        #pragma unroll
        for (int j = 6; j >= 1; j--) sfx *= z[j];
        evv[0] = sfx;
        if (half == 0) {
            __hip_bfloat16 o[8];
            #pragma unroll
            for (int i = 0; i < 8; i++) o[i] = __float2bfloat16(evv[i]);
            evB0 = *(bf16x8*)o;
        } else {
            evB0 = (bf16x8){};
            evB0[0] = (__bf16)1.0f;   // unit vector -> bias path via k=8 slot
        }
    }
    // --- stage b1 (bf16, permuted by p) into LDS
    for (int i = tid; i < KDIM; i += 256) {
        int q2 = (i >> 2) & 3;
        int src = i + ((q2 == 1) ? 4 : (q2 == 2) ? -4 : 0);
        b1h[i] = __float2bfloat16(b1[src]);
    }

    // B staging: wave stages frags f = wave*2, wave*2+1 (8 frags = 4 ni x 2 t)
    const __hip_bfloat16* gBp[2];
    #pragma unroll
    for (int i = 0; i < 2; i++) {
        int f = wave * 2 + i, ni = f >> 1, t = f & 1;
        gBp[i] = W2b + (size_t)(bn*BN + ni*32 + l31) * KDIM + t*16 + half*8;
    }
    // W1 per-lane row pointer (half0 lanes consume; permuted row baked in)
    const __hip_bfloat16* gW1p = W1bg + (size_t)prow * 8;

    // prologue: stage tile 0 -> Bs[0]; load w1f for tile 0
    gload_lds16(gBp[0], &Bs[0][(wave*2 + 0) * 512]); gBp[0] += 32;
    gload_lds16(gBp[1], &Bs[0][(wave*2 + 1) * 512]); gBp[1] += 32;
    bf16x8 w1f_cur = {};
    if (half == 0) w1f_cur = *(const bf16x8*)gW1p;   // rows k0=0
    __syncthreads();   // b1h visible; tile-0 staging drained

    const f32x16 z16 = {};
    f32x16 acc[4] = {};   // [ni]

    // iter T (buf = T%3): stage tile T+1 -> buf (T+1)%3; prefetch w1f(T+1);
    // MFMA1(w1f_cur) + pack; vmcnt(3) [2 stage + 1 w1f newer]; s_barrier;
    // 8 MFMA2 on Bs[buf].
#define K_ITER(T, BUF, DO_NEXT, VMC) do {                                     \
        if (DO_NEXT) {                                                        \
            gload_lds16(gBp[0], &Bs[((BUF) + 1) % 3][(wave*2 + 0) * 512]);    \
            gload_lds16(gBp[1], &Bs[((BUF) + 1) % 3][(wave*2 + 1) * 512]);    \
            gBp[0] += 32; gBp[1] += 32;                                       \
        }                                                                     \
        bf16x8 w1f_next = {};                                                 \
        if (DO_NEXT && half == 0)                                             \
            w1f_next = *(const bf16x8*)(gW1p + (size_t)((T) + 1) * 32 * 8);   \
        bf16x8 a_use = w1f_cur;                                               \
        if (half) {                                                           \
            a_use = (bf16x8){};                                               \
            a_use[0] = *(const __bf16*)&b1h[(T) * 32 + l31];                  \
        }                                                                     \
        f32x16 h = __builtin_amdgcn_mfma_f32_32x32x16_bf16(a_use, evB0, z16, 0, 0, 0); \
        bf16x8 af0, af1;                                                      \
        h_to_af(h, af0, af1);                                                 \
        asm volatile("s_waitcnt vmcnt(" VMC ")" ::: "memory");                \
        __builtin_amdgcn_s_barrier();                                         \
        _Pragma("unroll")                                                     \
        for (int ni = 0; ni < 4; ni++) {                                      \
            bf16x8 bf0 = *(bf16x8*)&Bs[BUF][(ni*2 + 0) * 512 + lane * 8];     \
            acc[ni] = __builtin_amdgcn_mfma_f32_32x32x16_bf16(af0, bf0, acc[ni], 0, 0, 0); \
            bf16x8 bf1 = *(bf16x8*)&Bs[BUF][(ni*2 + 1) * 512 + lane * 8];     \
            acc[ni] = __builtin_amdgcn_mfma_f32_32x32x16_bf16(af1, bf1, acc[ni], 0, 0, 0); \
        }                                                                     \
        w1f_cur = w1f_next;                                                   \
    } while (0)

    // 63 = 21 groups of 3 (iters 0..62, all staging next), then iter 63 alone
    for (int it0 = 0; it0 < 63; it0 += 3) {
        K_ITER(it0 + 0, 0, 1, "3");
        K_ITER(it0 + 1, 1, 1, "3");
        K_ITER(it0 + 2, 2, 1, "3");
    }
    K_ITER(63, 0, 0, "0");

#undef K_ITER

    // epilogue: 32x32 C/D layout: col = lane&31, row = (r&3)+8*(r>>2)+4*half
    int rbase = bm*BM + wave*32 + 4*half;
    #pragma unroll
    for (int ni = 0; ni < 4; ni++) {
        int col = bn*BN + ni*32 + l31;
        float bias = b2[col];
        #pragma unroll
        for (int r = 0; r < 16; r++) {
            int row = rbase + (r & 3) + 8 * (r >> 2);
            C[(size_t)row * EMB + col] = acc[ni][r] + bias;
        }
    }
}

extern "C" void kernel_launch(void* const* d_in, const int* in_sizes, int n_in,
                              void* d_out, int out_size, void* d_ws, size_t ws_size,
                              hipStream_t stream) {
    const float* x      = (const float*)d_in[0];  // [16,2048,8]
    const float* params = (const float*)d_in[1];  // [8,3]
    const float* W1     = (const float*)d_in[2];  // [2048,8]
    const float* b1     = (const float*)d_in[3];  // [2048]
    const float* W2     = (const float*)d_in[4];  // [512,2048]
    const float* b2     = (const float*)d_in[5];  // [512]
    float* out = (float*)d_out;                   // [32768,512]

    char* ws = (char*)d_ws;
    __hip_bfloat16* W2b  = (__hip_bfloat16*)ws;              // 2 MB
    __hip_bfloat16* W1bg = (__hip_bfloat16*)(ws + 2097152);  // 32 KB

    k_prep<<<1040, 256, 0, stream>>>(W2, W1, W2b, W1bg);
    k_gemm<<<(NS/BM) * (EMB/BN), 256, 0, stream>>>(x, params, W1bg, b1, W2b, b2, out);
}

// Round 14
// 151.453 us; speedup vs baseline: 1.0649x; 1.0649x over previous
//
#include <hip/hip_runtime.h>
#include <hip/hip_bf16.h>

#define NS 32768          // B*S samples
#define EMB 512
#define KDIM 2048
#define BM 256
#define BN 256
#define NPHASE (KDIM / 32)  // 64 phases, one 32-K chunk each

typedef float f32x16 __attribute__((ext_vector_type(16)));
typedef __bf16 bf16x8 __attribute__((ext_vector_type(8)));
typedef __bf16 bf16x2 __attribute__((ext_vector_type(2)));
typedef unsigned int u32;
typedef const __attribute__((address_space(1))) u32* gptr_t;
typedef __attribute__((address_space(3))) u32* lptr_t;

__device__ __forceinline__ void gload_lds16(const void* g, void* l) {
    __builtin_amdgcn_global_load_lds((gptr_t)g, (lptr_t)l, 16, 0, 0);
}

// pack two relu'd floats into one u32 of 2 bf16 (v_cvt_pk_bf16_f32)
__device__ __forceinline__ u32 pkrelu(float lo, float hi) {
    union { bf16x2 h; u32 u; } c;
    c.h[0] = (__bf16)fmaxf(lo, 0.f);
    c.h[1] = (__bf16)fmaxf(hi, 0.f);
    return c.u;
}

__device__ __forceinline__ bf16x8 mk_af(u32 a, u32 b, u32 c, u32 d) {
    union { u32 u[4]; bf16x8 v; } t;
    t.u[0] = a; t.u[1] = b; t.u[2] = c; t.u[3] = d;
    return t.v;
}

// GEMM1 C/D regs -> two GEMM2 A-fragments (hidden pre-permutation verified
// r5-r13): af0 = regs 0..7 pairwise-packed, af1 = regs 8..15. No cross-lane.
__device__ __forceinline__ void h_to_af(const f32x16 h, bf16x8& af0, bf16x8& af1) {
    af0 = mk_af(pkrelu(h[0], h[1]),  pkrelu(h[2], h[3]),
                pkrelu(h[4], h[5]),  pkrelu(h[6], h[7]));
    af1 = mk_af(pkrelu(h[8], h[9]),  pkrelu(h[10], h[11]),
                pkrelu(h[12], h[13]), pkrelu(h[14], h[15]));
}

// ---- prep: W2 -> bf16 (1024 blocks); W1 -> bf16 (16 blocks) ----
__global__ __launch_bounds__(256) void k_prep(const float* __restrict__ W2,
                                              const float* __restrict__ W1,
                                              __hip_bfloat16* __restrict__ W2b,
                                              __hip_bfloat16* __restrict__ W1bg) {
    int t = threadIdx.x;
    if (blockIdx.x < 1024) {
        int i = (blockIdx.x * 256 + t) * 4;
        float4 v = *(const float4*)(W2 + i);
        __hip_bfloat16 o[4];
        o[0] = __float2bfloat16(v.x); o[1] = __float2bfloat16(v.y);
        o[2] = __float2bfloat16(v.z); o[3] = __float2bfloat16(v.w);
        *(ulong1*)(W2b + i) = *(ulong1*)o;
    } else {
        int j = (blockIdx.x - 1024) * 1024 + t * 4;   // 16 blocks x 1024
        float4 w = *(const float4*)(W1 + j);
        __hip_bfloat16 p[4];
        p[0] = __float2bfloat16(w.x); p[1] = __float2bfloat16(w.y);
        p[2] = __float2bfloat16(w.z); p[3] = __float2bfloat16(w.w);
        *(ulong1*)(W1bg + j) = *(ulong1*)p;
    }
}

// ---- fused: C[256,256-tile] = relu(ev @ W1^T + b1) @ W2b^T + b2 ----
// 8-PHASE TEMPLATE PORT (m201 structure): 256x256 tile, 8 waves (4wm x 2wn),
// grid 256 = exactly 1 block/CU. Per phase (one 32-K chunk, 64 phases):
//   pre-barrier: { t0 B-frag ds_reads + w1f read;  stage chunk p+3 (2 gload) }
//   vmcnt(4)  -> s_barrier -> lgkmcnt(0)
//   setprio(1): 2xMFMA1 -> pack -> issue t1 ds_reads -> 8xMFMA2(t0)
//               -> 8xMFMA2(t1)  ; setprio(0) -> s_barrier
// LDS-read latency lands under the barrier wait; stage loads stay in flight
// across barriers (counted vmcnt, never 0 mid-loop).
// Race-freedom: stage at p writes buf (p-1)&3; its readers lgkm-completed
// before BARRIER2(p-1), which precedes p's issue. Reads at p of buf p&3 are
// covered by vmcnt at p-1 + BARRIER ordering. 4 buffers, prefetch dist 3.
// GEMM1-on-MFMA (b1 in k=8 slot), hidden pre-perm, reuse-2 — verified r5-r13.
__global__ __launch_bounds__(512, 2) void k_gemm(
        const float* __restrict__ x,       // [NS, 8]
        const float* __restrict__ params,  // [8, 3]
        const __hip_bfloat16* __restrict__ W1bg,  // [2048, 8] bf16
        const float* __restrict__ b1,      // [2048]
        const __hip_bfloat16* __restrict__ W2b,   // [512, 2048] bf16
        const float* __restrict__ b2,      // [512]
        float* __restrict__ C) {           // [NS, 512]
    __shared__ __hip_bfloat16 Bs[4][16 * 512]; // 4 x 16 KB = 64 KB
    __shared__ __hip_bfloat16 W1s[KDIM * 8];   // 32 KB (rows permuted by p)
    __shared__ __hip_bfloat16 b1h[KDIM];       // 4 KB  (permuted by p)
    __shared__ __hip_bfloat16 evs[BM * 8];     // 4 KB  -> 104 KB, 1 blk/CU

    int tid = threadIdx.x, wave = tid >> 6, lane = tid & 63;
    int l31 = lane & 31, half = lane >> 5;
    int wm = wave >> 1, wn = wave & 1;
    int bx = blockIdx.x, bm = bx >> 1, bn = bx & 1;

    // --- inline ev for this block's 256 rows (threads 0..255, 1 sample each)
    if (tid < 256) {
        float K1[8], K2[8];
        #pragma unroll
        for (int i = 0; i < 8; i++) {
            float a = params[i*3+0], b = params[i*3+1], g = params[i*3+2];
            float sa, ca, sb, cb, sg, cg;
            __sincosf(a, &sa, &ca);
            __sincosf(b, &sb, &cb);
            __sincosf(g, &sg, &cg);
            K1[i] = sa*sb*sg + ca*cg;
            K2[i] = cb*sg;
        }
        int n = bm * BM + tid;
        float4 x0 = *(const float4*)(x + (size_t)n*8);
        float4 x1 = *(const float4*)(x + (size_t)n*8 + 4);
        float xs[8] = {x0.x, x0.y, x0.z, x0.w, x1.x, x1.y, x1.z, x1.w};
        float z[8];
        #pragma unroll
        for (int i = 0; i < 8; i++) {
            float s, c;
            __sincosf(xs[i], &s, &c);
            z[i] = c * K1[i] - s * K2[i];
        }
        float evv[8];
        float p = z[0];
        #pragma unroll
        for (int j = 1; j < 8; j++) { p *= z[j]; evv[j] = p; }
        float sfx = z[7];
        #pragma unroll
        for (int j = 6; j >= 1; j--) sfx *= z[j];
        evv[0] = sfx;
        __hip_bfloat16 o[8];
        #pragma unroll
        for (int i = 0; i < 8; i++) o[i] = __float2bfloat16(evv[i]);
        *(bf16x8*)&evs[tid * 8] = *(bf16x8*)o;
    }
    // --- stage W1 (bf16) + b1 (bf16) into LDS, rows permuted by p(i):
    //     within each 32-chunk, swap quads 1<->2 and 5<->6.
    for (int i = tid; i < KDIM; i += 512) {
        int q = (i >> 2) & 3;
        int src = i + ((q == 1) ? 4 : (q == 2) ? -4 : 0);
        *(bf16x8*)&W1s[i * 8] = *(const bf16x8*)(W1bg + (size_t)src * 8);
        b1h[i] = __float2bfloat16(b1[src]);
    }

    // B staging: 16 frags/chunk; f = wnf*8 + ni*2 + t. Wave stages f=wave*2,+1.
    const __hip_bfloat16* gBp0;
    const __hip_bfloat16* gBp1;
    {
        int f0 = wave * 2, f1 = wave * 2 + 1;
        int r0 = bn*BN + (f0 >> 3)*128 + ((f0 >> 1) & 3)*32 + l31;
        int r1 = bn*BN + (f1 >> 3)*128 + ((f1 >> 1) & 3)*32 + l31;
        gBp0 = W2b + (size_t)r0 * KDIM + (f0 & 1)*16 + half*8;
        gBp1 = W2b + (size_t)r1 * KDIM + (f1 & 1)*16 + half*8;
    }
    // prologue: stage chunks 0,1,2 -> Bs[0..2]
    #pragma unroll
    for (int c = 0; c < 3; c++) {
        gload_lds16(gBp0, &Bs[c][(wave*2 + 0) * 512]); gBp0 += 32;
        gload_lds16(gBp1, &Bs[c][(wave*2 + 1) * 512]); gBp1 += 32;
    }
    __syncthreads();   // evs/W1s/b1h + chunks 0..2 staged+drained

    // GEMM1 B-operands: half0 = the wave's two 32-row ev groups; half1 = unit
    bf16x8 evB0, evB1;
    if (half == 0) {
        evB0 = *(bf16x8*)&evs[(wm * 64 +      l31) * 8];
        evB1 = *(bf16x8*)&evs[(wm * 64 + 32 + l31) * 8];
    } else {
        evB0 = (bf16x8){};
        evB0[0] = (__bf16)1.0f;
        evB1 = evB0;
    }
    const f32x16 z16 = {};   // loop-invariant zero C-in for GEMM1
    const int fbase = wn * 8;  // this wave's fragment column-group

    f32x16 acc[8] = {};   // [rg*4 + ni]

#define K_PHASE(T, BUF, DO_STAGE, VMC) do {                                   \
        const int k0 = (T) * 32;                                              \
        /* pre-barrier reads: t0 B-frags + w1f (land during barrier wait) */  \
        bf16x8 bf0[4];                                                        \
        _Pragma("unroll")                                                     \
        for (int ni = 0; ni < 4; ni++)                                        \
            bf0[ni] = *(bf16x8*)&Bs[BUF][(fbase + ni*2 + 0) * 512 + lane * 8];\
        bf16x8 w1f;                                                           \
        if (half == 0) {                                                      \
            w1f = *(const bf16x8*)&W1s[(k0 + l31) * 8];                       \
        } else {                                                              \
            w1f = (bf16x8){};                                                 \
            w1f[0] = *(const __bf16*)&b1h[k0 + l31];                          \
        }                                                                     \
        if (DO_STAGE) {                                                       \
            gload_lds16(gBp0, &Bs[((BUF) + 3) & 3][(wave*2 + 0) * 512]);      \
            gload_lds16(gBp1, &Bs[((BUF) + 3) & 3][(wave*2 + 1) * 512]);      \
            gBp0 += 32; gBp1 += 32;                                           \
        }                                                                     \
        asm volatile("s_waitcnt vmcnt(" VMC ")" ::: "memory");                \
        __builtin_amdgcn_s_barrier();                                         \
        asm volatile("s_waitcnt lgkmcnt(0)" ::: "memory");                    \
        __builtin_amdgcn_sched_barrier(0);                                    \
        __builtin_amdgcn_s_setprio(1);                                        \
        f32x16 h0 = __builtin_amdgcn_mfma_f32_32x32x16_bf16(w1f, evB0, z16, 0, 0, 0); \
        f32x16 h1 = __builtin_amdgcn_mfma_f32_32x32x16_bf16(w1f, evB1, z16, 0, 0, 0); \
        bf16x8 af00, af01, af10, af11;                                        \
        h_to_af(h0, af00, af01);                                              \
        h_to_af(h1, af10, af11);                                              \
        /* t1 reads issued here; fly under the t0 MFMA2 cluster */            \
        bf16x8 bf1[4];                                                        \
        _Pragma("unroll")                                                     \
        for (int ni = 0; ni < 4; ni++)                                        \
            bf1[ni] = *(bf16x8*)&Bs[BUF][(fbase + ni*2 + 1) * 512 + lane * 8];\
        _Pragma("unroll")                                                     \
        for (int ni = 0; ni < 4; ni++) {                                      \
            acc[ni]     = __builtin_amdgcn_mfma_f32_32x32x16_bf16(af00, bf0[ni], acc[ni],     0, 0, 0); \
            acc[4 + ni] = __builtin_amdgcn_mfma_f32_32x32x16_bf16(af10, bf0[ni], acc[4 + ni], 0, 0, 0); \
        }                                                                     \
        _Pragma("unroll")                                                     \
        for (int ni = 0; ni < 4; ni++) {                                      \
            acc[ni]     = __builtin_amdgcn_mfma_f32_32x32x16_bf16(af01, bf1[ni], acc[ni],     0, 0, 0); \
            acc[4 + ni] = __builtin_amdgcn_mfma_f32_32x32x16_bf16(af11, bf1[ni], acc[4 + ni], 0, 0, 0); \
        }                                                                     \
        __builtin_amdgcn_s_setprio(0);                                        \
        __builtin_amdgcn_s_barrier();                                         \
    } while (0)

    for (int it0 = 0; it0 < NPHASE - 4; it0 += 4) {
        K_PHASE(it0 + 0, 0, 1, "4");
        K_PHASE(it0 + 1, 1, 1, "4");
        K_PHASE(it0 + 2, 2, 1, "4");
        K_PHASE(it0 + 3, 3, 1, "4");
    }
    // tail: phase 60 stages chunk 63; 61-63 drain (counted: 2,0,0)
    K_PHASE(NPHASE - 4, 0, 1, "4");
    K_PHASE(NPHASE - 3, 1, 0, "2");
    K_PHASE(NPHASE - 2, 2, 0, "0");
    K_PHASE(NPHASE - 1, 3, 0, "0");

#undef K_PHASE

    // epilogue: 32x32 C/D layout: col = lane&31, row = (r&3)+8*(r>>2)+4*half
    #pragma unroll
    for (int rg = 0; rg < 2; rg++) {
        int rbase = bm*BM + wm*64 + rg*32 + 4*half;
        #pragma unroll
        for (int ni = 0; ni < 4; ni++) {
            int col = bn*BN + wn*128 + ni*32 + l31;
            float bias = b2[col];
            #pragma unroll
            for (int r = 0; r < 16; r++) {
                int row = rbase + (r & 3) + 8 * (r >> 2);
                C[(size_t)row * EMB + col] = acc[rg*4 + ni][r] + bias;
            }
        }
    }
}

extern "C" void kernel_launch(void* const* d_in, const int* in_sizes, int n_in,
                              void* d_out, int out_size, void* d_ws, size_t ws_size,
                              hipStream_t stream) {
    const float* x      = (const float*)d_in[0];  // [16,2048,8]
    const float* params = (const float*)d_in[1];  // [8,3]
    const float* W1     = (const float*)d_in[2];  // [2048,8]
    const float* b1     = (const float*)d_in[3];  // [2048]
    const float* W2     = (const float*)d_in[4];  // [512,2048]
    const float* b2     = (const float*)d_in[5];  // [512]
    float* out = (float*)d_out;                   // [32768,512]

    char* ws = (char*)d_ws;
    __hip_bfloat16* W2b  = (__hip_bfloat16*)ws;              // 2 MB
    __hip_bfloat16* W1bg = (__hip_bfloat16*)(ws + 2097152);  // 32 KB

    k_prep<<<1040, 256, 0, stream>>>(W2, W1, W2b, W1bg);
    k_gemm<<<(NS/BM) * (EMB/BN), 512, 0, stream>>>(x, params, W1bg, b1, W2b, b2, out);
}

// Round 15
// 146.668 us; speedup vs baseline: 1.0996x; 1.0326x over previous
//
#include <hip/hip_runtime.h>
#include <hip/hip_bf16.h>

#define NS 32768          // B*S samples
#define EMB 512
#define KDIM 2048
#define BM 256
#define BN 128
#define NITER (KDIM / 32)   // 64

typedef float f32x16 __attribute__((ext_vector_type(16)));
typedef __bf16 bf16x8 __attribute__((ext_vector_type(8)));
typedef __bf16 bf16x2 __attribute__((ext_vector_type(2)));
typedef unsigned int u32;
typedef const __attribute__((address_space(1))) u32* gptr_t;
typedef __attribute__((address_space(3))) u32* lptr_t;

__device__ __forceinline__ void gload_lds16(const void* g, void* l) {
    __builtin_amdgcn_global_load_lds((gptr_t)g, (lptr_t)l, 16, 0, 0);
}

// pack two relu'd floats into one u32 of 2 bf16 (v_cvt_pk_bf16_f32)
__device__ __forceinline__ u32 pkrelu(float lo, float hi) {
    union { bf16x2 h; u32 u; } c;
    c.h[0] = (__bf16)fmaxf(lo, 0.f);
    c.h[1] = (__bf16)fmaxf(hi, 0.f);
    return c.u;
}

__device__ __forceinline__ bf16x8 mk_af(u32 a, u32 b, u32 c, u32 d) {
    union { u32 u[4]; bf16x8 v; } t;
    t.u[0] = a; t.u[1] = b; t.u[2] = c; t.u[3] = d;
    return t.v;
}

// GEMM1 C/D regs -> two GEMM2 A-fragments. With the hidden-index
// pre-permutation (W1/b1 rows permuted by p(i) at stage time, verified r5-r14),
// D reg r at (l31,half) holds H_orig[k0 + t*16 + half*8 + j] in A-frag
// order: af0 = regs 0..7 pairwise-packed, af1 = regs 8..15. No cross-lane.
__device__ __forceinline__ void h_to_af(const f32x16 h, bf16x8& af0, bf16x8& af1) {
    af0 = mk_af(pkrelu(h[0], h[1]),  pkrelu(h[2], h[3]),
                pkrelu(h[4], h[5]),  pkrelu(h[6], h[7]));
    af1 = mk_af(pkrelu(h[8], h[9]),  pkrelu(h[10], h[11]),
                pkrelu(h[12], h[13]), pkrelu(h[14], h[15]));
}

// ---- prep: W2 -> bf16 (1024 blocks); W1 -> bf16 (16 blocks) ----
__global__ __launch_bounds__(256) void k_prep(const float* __restrict__ W2,
                                              const float* __restrict__ W1,
                                              __hip_bfloat16* __restrict__ W2b,
                                              __hip_bfloat16* __restrict__ W1bg) {
    int t = threadIdx.x;
    if (blockIdx.x < 1024) {
        int i = (blockIdx.x * 256 + t) * 4;
        float4 v = *(const float4*)(W2 + i);
        __hip_bfloat16 o[4];
        o[0] = __float2bfloat16(v.x); o[1] = __float2bfloat16(v.y);
        o[2] = __float2bfloat16(v.z); o[3] = __float2bfloat16(v.w);
        *(ulong1*)(W2b + i) = *(ulong1*)o;
    } else {
        int j = (blockIdx.x - 1024) * 1024 + t * 4;   // 16 blocks x 1024
        float4 w = *(const float4*)(W1 + j);
        __hip_bfloat16 p[4];
        p[0] = __float2bfloat16(w.x); p[1] = __float2bfloat16(w.y);
        p[2] = __float2bfloat16(w.z); p[3] = __float2bfloat16(w.w);
        *(ulong1*)(W1bg + j) = *(ulong1*)p;
    }
}

// ---- fused: C[256,128-tile] = relu(ev @ W1^T + b1) @ W2b^T + b2 ----
// SESSION-BEST structure (r7, 78.3us k_gemm / 149.2us total), final revert:
//  * Bs quad-buffered (4 x 8 KB), prefetch distance 2.
//  * ONE raw s_barrier per K-iter; counted s_waitcnt vmcnt(4) (tail 2,0)
//    BEFORE it -> the next 2 tiles' global_load_lds stay in flight across
//    the barrier (drain-to-0 per iter was the ~25% stall of r4/r5).
//  * GEMM1 on the MFMA pipe: H-chunk = mfma(W1-rows zero-padded K, ev),
//    b1 folded via the unused k=8 slot (half1 A={b1,0..}, B={1,0..}).
//  * Hidden-index pre-permutation p(i) at W1/b1 stage time -> GEMM1 D regs
//    land directly in GEMM2 A-frag order (no cross-lane ops).
//  * reuse-2: each B-frag ds_read_b128 feeds two MFMAs (two 32-row groups).
//  * s_setprio(1) around the MFMA2 cluster (r12 ablation: neutral; r7's
//    exact best config retained).
// Measured nulls on this structure (kept out): AF-one-ahead (r9 +3us),
// pair-barrier (r10 +5us), 3-blocks/CU (r13 +18us), 8-phase port (r14 +4us).
__global__ __launch_bounds__(256, 2) void k_gemm(
        const float* __restrict__ x,       // [NS, 8]
        const float* __restrict__ params,  // [8, 3]
        const __hip_bfloat16* __restrict__ W1bg,  // [2048, 8] bf16
        const float* __restrict__ b1,      // [2048]
        const __hip_bfloat16* __restrict__ W2b,   // [512, 2048] bf16
        const float* __restrict__ b2,      // [512]
        float* __restrict__ C) {           // [NS, 512]
    __shared__ __hip_bfloat16 Bs[4][8 * 512];  // quad-buffered, 4 x 8 KB
    __shared__ __hip_bfloat16 W1s[KDIM * 8];   // 32 KB (rows permuted by p)
    __shared__ __hip_bfloat16 b1h[KDIM];       // 4 KB  (permuted by p)
    __shared__ __hip_bfloat16 evs[BM * 8];     // 4 KB  -> total 72 KB, 2 blk/CU

    int tid = threadIdx.x, wave = tid >> 6, lane = tid & 63;
    int l31 = lane & 31, half = lane >> 5;
    int bx = blockIdx.x, bm = bx >> 2, bn = bx & 3;

    // --- inline ev for this block's 256 rows (1 sample per thread)
    {
        float K1[8], K2[8];
        #pragma unroll
        for (int i = 0; i < 8; i++) {
            float a = params[i*3+0], b = params[i*3+1], g = params[i*3+2];
            float sa, ca, sb, cb, sg, cg;
            __sincosf(a, &sa, &ca);
            __sincosf(b, &sb, &cb);
            __sincosf(g, &sg, &cg);
            K1[i] = sa*sb*sg + ca*cg;
            K2[i] = cb*sg;
        }
        int n = bm * BM + tid;
        float4 x0 = *(const float4*)(x + (size_t)n*8);
        float4 x1 = *(const float4*)(x + (size_t)n*8 + 4);
        float xs[8] = {x0.x, x0.y, x0.z, x0.w, x1.x, x1.y, x1.z, x1.w};
        float z[8];
        #pragma unroll
        for (int i = 0; i < 8; i++) {
            float s, c;
            __sincosf(xs[i], &s, &c);
            z[i] = c * K1[i] - s * K2[i];
        }
        float evv[8];
        float p = z[0];
        #pragma unroll
        for (int j = 1; j < 8; j++) { p *= z[j]; evv[j] = p; }
        float sfx = z[7];
        #pragma unroll
        for (int j = 6; j >= 1; j--) sfx *= z[j];
        evv[0] = sfx;
        __hip_bfloat16 o[8];
        #pragma unroll
        for (int i = 0; i < 8; i++) o[i] = __float2bfloat16(evv[i]);
        *(bf16x8*)&evs[tid * 8] = *(bf16x8*)o;
    }
    // --- stage W1 (bf16) + b1 (bf16) into LDS, rows permuted by p(i):
    //     within each 32-chunk, swap quads 1<->2 and 5<->6.
    for (int i = tid; i < KDIM; i += 256) {
        int q = (i >> 2) & 3;
        int src = i + ((q == 1) ? 4 : (q == 2) ? -4 : 0);
        *(bf16x8*)&W1s[i * 8] = *(const bf16x8*)(W1bg + (size_t)src * 8);
        b1h[i] = __float2bfloat16(b1[src]);
    }

    // B staging: wave stages frags f = wave*2, wave*2+1  (8 frags = 4 ni x 2 t)
    const __hip_bfloat16* gBp[2];
    #pragma unroll
    for (int i = 0; i < 2; i++) {
        int f = wave * 2 + i, ni = f >> 1, t = f & 1;
        gBp[i] = W2b + (size_t)(bn*BN + ni*32 + l31) * KDIM + t*16 + half*8;
    }
    // prologue: stage tiles 0 and 1 -> Bs[0], Bs[1]
    #pragma unroll
    for (int b = 0; b < 2; b++) {
        #pragma unroll
        for (int i = 0; i < 2; i++) {
            gload_lds16(gBp[i], &Bs[b][(wave*2 + i) * 512]);
            gBp[i] += 32;
        }
    }

    __syncthreads();   // evs/W1s/b1h written; tiles 0,1 staged+drained

    // GEMM1 B-operands: half0 = the wave's two 32-row ev groups; half1 = unit
    bf16x8 evB0, evB1;
    if (half == 0) {
        evB0 = *(bf16x8*)&evs[(wave * 64 +      l31) * 8];
        evB1 = *(bf16x8*)&evs[(wave * 64 + 32 + l31) * 8];
    } else {
        evB0 = (bf16x8){};
        evB0[0] = (__bf16)1.0f;
        evB1 = evB0;
    }
    const f32x16 z16 = {};   // loop-invariant zero C-in for GEMM1

    f32x16 acc[8] = {};   // [rg*4 + ni]

#define COMPUTE_AF(K0, A00, A01, A10, A11) do {                               \
        bf16x8 w1f;                                                           \
        if (half == 0) {                                                      \
            w1f = *(const bf16x8*)&W1s[((K0) + l31) * 8];                     \
        } else {                                                              \
            w1f = (bf16x8){};                                                 \
            w1f[0] = *(const __bf16*)&b1h[(K0) + l31];                        \
        }                                                                     \
        f32x16 h0 = __builtin_amdgcn_mfma_f32_32x32x16_bf16(w1f, evB0, z16, 0, 0, 0); \
        h_to_af(h0, A00, A01);                                                \
        f32x16 h1 = __builtin_amdgcn_mfma_f32_32x32x16_bf16(w1f, evB1, z16, 0, 0, 0); \
        h_to_af(h1, A10, A11);                                                \
    } while (0)

#define GEMM2_STEP(CB, A00, A01, A10, A11) do {                               \
        __builtin_amdgcn_s_setprio(1);                                        \
        _Pragma("unroll")                                                     \
        for (int ni = 0; ni < 4; ni++) {                                      \
            bf16x8 bf0 = *(bf16x8*)&Bs[CB][(ni*2 + 0) * 512 + lane * 8];      \
            acc[ni]     = __builtin_amdgcn_mfma_f32_32x32x16_bf16(A00, bf0, acc[ni],     0, 0, 0); \
            acc[4 + ni] = __builtin_amdgcn_mfma_f32_32x32x16_bf16(A10, bf0, acc[4 + ni], 0, 0, 0); \
            bf16x8 bf1 = *(bf16x8*)&Bs[CB][(ni*2 + 1) * 512 + lane * 8];      \
            acc[ni]     = __builtin_amdgcn_mfma_f32_32x32x16_bf16(A01, bf1, acc[ni],     0, 0, 0); \
            acc[4 + ni] = __builtin_amdgcn_mfma_f32_32x32x16_bf16(A11, bf1, acc[4 + ni], 0, 0, 0); \
        }                                                                     \
        __builtin_amdgcn_s_setprio(0);                                        \
    } while (0)

    // one K-iteration: stage tile T+2, GEMM1(T), counted-vmcnt wait, raw
    // barrier, GEMM2(T).  VMC is a string literal ("4"/"2"/"0").
#define K_ITER(T, BUF, DO_STAGE, VMC) do {                                    \
        if (DO_STAGE) {                                                       \
            gload_lds16(gBp[0], &Bs[((BUF) + 2) & 3][(wave*2 + 0) * 512]);    \
            gload_lds16(gBp[1], &Bs[((BUF) + 2) & 3][(wave*2 + 1) * 512]);    \
            gBp[0] += 32; gBp[1] += 32;                                       \
        }                                                                     \
        COMPUTE_AF((T) * 32, aA00, aA01, aA10, aA11);                         \
        asm volatile("s_waitcnt vmcnt(" VMC ")" ::: "memory");                \
        __builtin_amdgcn_s_barrier();                                         \
        GEMM2_STEP(BUF, aA00, aA01, aA10, aA11);                              \
    } while (0)

    bf16x8 aA00, aA01, aA10, aA11;

    for (int it0 = 0; it0 < NITER - 4; it0 += 4) {
        K_ITER(it0 + 0, 0, 1, "4");
        K_ITER(it0 + 1, 1, 1, "4");
        K_ITER(it0 + 2, 2, 1, "4");
        K_ITER(it0 + 3, 3, 1, "4");
    }
    // final group: t = 60..63 (stages tiles 62, 63; then drain 2, 0)
    K_ITER(NITER - 4, 0, 1, "4");
    K_ITER(NITER - 3, 1, 1, "4");
    K_ITER(NITER - 2, 2, 0, "2");
    K_ITER(NITER - 1, 3, 0, "0");

#undef K_ITER
#undef COMPUTE_AF
#undef GEMM2_STEP

    // epilogue: 32x32 C/D layout: col = lane&31, row = (r&3)+8*(r>>2)+4*half
    #pragma unroll
    for (int rg = 0; rg < 2; rg++) {
        int rbase = bm*BM + wave*64 + rg*32 + 4*half;
        #pragma unroll
        for (int ni = 0; ni < 4; ni++) {
            int col = bn*BN + ni*32 + l31;
            float bias = b2[col];
            #pragma unroll
            for (int r = 0; r < 16; r++) {
                int row = rbase + (r & 3) + 8 * (r >> 2);
                C[(size_t)row * EMB + col] = acc[rg*4 + ni][r] + bias;
            }
        }
    }
}

extern "C" void kernel_launch(void* const* d_in, const int* in_sizes, int n_in,
                              void* d_out, int out_size, void* d_ws, size_t ws_size,
                              hipStream_t stream) {
    const float* x      = (const float*)d_in[0];  // [16,2048,8]
    const float* params = (const float*)d_in[1];  // [8,3]
    const float* W1     = (const float*)d_in[2];  // [2048,8]
    const float* b1     = (const float*)d_in[3];  // [2048]
    const float* W2     = (const float*)d_in[4];  // [512,2048]
    const float* b2     = (const float*)d_in[5];  // [512]
    float* out = (float*)d_out;                   // [32768,512]

    char* ws = (char*)d_ws;
    __hip_bfloat16* W2b  = (__hip_bfloat16*)ws;              // 2 MB
    __hip_bfloat16* W1bg = (__hip_bfloat16*)(ws + 2097152);  // 32 KB

    k_prep<<<1040, 256, 0, stream>>>(W2, W1, W2b, W1bg);
    k_gemm<<<(NS/BM) * (EMB/BN), 256, 0, stream>>>(x, params, W1bg, b1, W2b, b2, out);
}